// Round 16
// baseline (1676894.727 us; speedup 1.0000x reference)
//
#include <hip/hip_runtime.h>
#include <math.h>

#define N   96
#define N2  9216
#define NPAIR_SYM 4656     // 96*97/2 (p<=q) pair-blocks of G

#define M_COLD 16
#define M_WARM 5
#define CONV_TOL 1e-2f
#define FUSED_GRID 768     // 3/CU co-resident (LDS ~46KB*3=141KB); coop-validated
#define FB_GRID 1024       // fallback contract grid
#define MAXIT 20
#define NBAR (MAXIT - 1)
#define GUARD_SPINS 3000000ull   // ~150ms: fail fast instead of 600s timeout

// ---- d_ws layout ----
// ints (from base):
#define OFFI_CTR  0                    // NBAR counters, stride 16 ints (64B each)
#define OFFI_CONV (NBAR * 16)          // fallback conv flag
// floats (from base):
#define OFF_JK    512                  // per-iteration J/K buffers: it t uses [(t-1)*2*N2, +2*N2)
#define JKFLOATS  (NBAR * 2 * N2)
#define OFF_V     (OFF_JK + JKFLOATS)  // fallback v (96)
#define OFF_U     (OFF_V + 128)        // fallback u (96)
#define OFF_GB    (OFF_U + 128)        // bf16 G-half: 4656*9216 ushorts
#define NEED_BF16_BYTES ((size_t)OFF_GB * 4 + (size_t)NPAIR_SYM * N2 * 2)

__device__ __forceinline__ unsigned short f2bf(float x) {
    unsigned u = __float_as_uint(x);
    unsigned r = (u + 0x7FFFu + ((u >> 16) & 1u)) >> 16;
    return (unsigned short)r;
}
__device__ __forceinline__ float bf2f(unsigned h) {
    return __uint_as_float(h << 16);
}
__device__ __forceinline__ void decode_pq(int pr, int& p_, int& q_) {
    int p = (int)((193.0 - sqrt(37249.0 - 8.0 * (double)pr)) * 0.5);
    if (p > 95) p = 95;
    if (p < 0) p = 0;
    while (p * 96 - p * (p - 1) / 2 > pr) --p;
    while ((p + 1) * 96 - (p + 1) * p / 2 <= pr) ++p;
    p_ = p;
    q_ = p + (pr - (p * 96 - p * (p - 1) / 2));
}

struct SMem {
    float mat[N * 97];          // contract: Ms ; eig: Fs
    float V[M_COLD][N];
    float v0[N], v1[N], v2[N], v3[N], v4[N], v5[N];
    float u_keep[N], v_keep[N]; // persistent across iterations (block-local)
    float alpha[M_COLD + 1], beta[M_COLD + 1], dred[M_COLD], wsml[M_COLD];
    double cp[M_COLD], dp[M_COLD];
    float scal[4];
    int meff, done, convl;
};

// ===========================================================================
// k_prep: zero barrier counters + conv flag + J/K buffers, AND convert the
// p<=q half of G to bf16 (disjoint writes; no ordering needed). One dispatch.
// Runs every kernel_launch -> graph replays always start from clean state.
// Dispatch-end L2 writeback makes Gb globally visible to k_scf.
// ===========================================================================
__global__ __launch_bounds__(256)
void k_prep(int* __restrict__ ctr, float* __restrict__ jk,
            const float* __restrict__ G, unsigned short* __restrict__ Gb,
            int doconv)
{
    const int gtid = blockIdx.x * blockDim.x + threadIdx.x;
    const int nth  = gridDim.x * blockDim.x;
    for (int i = gtid; i < NBAR * 16 + 16; i += nth) ctr[i] = 0;
    for (int i = gtid; i < JKFLOATS; i += nth) jk[i] = 0.f;
    if (doconv) {
        const int tid = threadIdx.x;
        for (int pr = blockIdx.x; pr < NPAIR_SYM; pr += (int)gridDim.x) {
            int p, q;
            decode_pq(pr, p, q);
            const float4* G4 = (const float4*)(G + (size_t)(p * N + q) * N2);
            uint2* Gb2 = (uint2*)(Gb + (size_t)pr * N2);
            for (int k = tid; k < N2 / 4; k += 256) {
                float4 f = G4[k];
                uint2 o;
                o.x = (unsigned)f2bf(f.x) | ((unsigned)f2bf(f.y) << 16);
                o.y = (unsigned)f2bf(f.z) | ((unsigned)f2bf(f.w) << 16);
                Gb2[k] = o;
            }
        }
    }
}

// ===========================================================================
// k_scf: persistent fused SCF, NO grid.sync (round-12/14 proven skeleton).
// Per iteration t>=1:
//   [all blocks] contract own pair-blocks (read pre-converted bf16 Gb)
//     -> atomicAdd into fresh J/K[t]
//   flush-free barrier: counter[t-1] atomicAdd + relaxed spin (data crosses
//     blocks ONLY via device-scope atomics; J/K read back via agent loads)
//   [ALL blocks, redundant] F=H+2J-K in LDS; warm Lanczos (Fp x = A(F(Ax)));
//     bisection; fp64 inverse iter; Ritz; u,v kept block-local;
//     identical inputs -> identical result in every block -> uniform break.
// ===========================================================================
__global__ __launch_bounds__(384)
void k_scf(const float* __restrict__ G, const unsigned short* __restrict__ Gb,
           const float* __restrict__ A, const float* __restrict__ H,
           const float* __restrict__ Enuc,
           float* __restrict__ jk, int* __restrict__ ctr,
           float* __restrict__ out, int bf16ok)
{
    __shared__ SMem sm;
    const int tid  = threadIdx.x;
    const int bid  = blockIdx.x;
    const int lane = tid & 63;
    const int wv   = tid >> 6;

    for (int it = 0; it < MAXIT; ++it) {
        float* Jb = jk + (size_t)(it > 0 ? it - 1 : 0) * 2 * N2;
        float* Kb = Jb + N2;

        // ---------------- contract phase ----------------
        if (it > 0) {
            for (int pr = bid; pr < NPAIR_SYM; pr += FUSED_GRID) {
                int p, q;
                decode_pq(pr, p, q);
                __syncthreads();   // sm.mat free; v_keep visible
                if (bf16ok) {
                    const uint4* Gb4 = (const uint4*)(Gb + (size_t)pr * N2);
                    for (int i = tid; i < N2 / 8; i += 384) {
                        uint4 u = Gb4[i];
                        int r = i / 12, s0 = (i - r * 12) * 8;
                        float* dst = &sm.mat[r * 97 + s0];
                        dst[0] = bf2f(u.x & 0xFFFFu); dst[1] = bf2f(u.x >> 16);
                        dst[2] = bf2f(u.y & 0xFFFFu); dst[3] = bf2f(u.y >> 16);
                        dst[4] = bf2f(u.z & 0xFFFFu); dst[5] = bf2f(u.z >> 16);
                        dst[6] = bf2f(u.w & 0xFFFFu); dst[7] = bf2f(u.w >> 16);
                    }
                } else {
                    const float4* G4 = (const float4*)(G + (size_t)(p * N + q) * N2);
                    for (int k = tid; k < N2 / 4; k += 384) {
                        float4 f = G4[k];
                        int r = k / 24, s4 = (k - r * 24) * 4;
                        float* dst = &sm.mat[r * 97 + s4];
                        dst[0] = f.x; dst[1] = f.y; dst[2] = f.z; dst[3] = f.w;
                    }
                }
                __syncthreads();
                if (tid < N) {                 // row dot
                    const float* row = &sm.mat[tid * 97];
                    float acc = 0.f;
                    #pragma unroll 8
                    for (int s = 0; s < N; ++s) acc += row[s] * sm.v_keep[s];
                    atomicAdd(&Kb[p * N + tid], sm.v_keep[q] * acc);
                    sm.v1[tid] = acc * sm.v_keep[tid];
                } else if (tid < 2 * N && p != q) {  // col dot
                    const int s = tid - N;
                    float acc = 0.f;
                    #pragma unroll 8
                    for (int r = 0; r < N; ++r) acc += sm.mat[r * 97 + s] * sm.v_keep[r];
                    atomicAdd(&Kb[q * N + s], sm.v_keep[p] * acc);
                    sm.v2[s] = acc * sm.v_keep[s];
                }
                __syncthreads();
                if (wv == 0) {                 // J[p,q]
                    float a = sm.v1[lane];
                    if (lane < 32) a += sm.v1[lane + 64];
                    #pragma unroll
                    for (int o = 32; o; o >>= 1) a += __shfl_xor(a, o);
                    if (lane == 0) atomicAdd(&Jb[p * N + q], a);
                } else if (wv == 1 && p != q) { // J[q,p]
                    float a = sm.v2[lane];
                    if (lane < 32) a += sm.v2[lane + 64];
                    #pragma unroll
                    for (int o = 32; o; o >>= 1) a += __shfl_xor(a, o);
                    if (lane == 0) atomicAdd(&Jb[q * N + p], a);
                }
            }
            __syncthreads();   // drains outstanding atomics (vmcnt before s_barrier)
            // ---- flush-free barrier on counter[it-1] ----
            if (tid == 0) {
                int* c = ctr + (size_t)(it - 1) * 16;
                __hip_atomic_fetch_add(c, 1, __ATOMIC_RELEASE, __HIP_MEMORY_SCOPE_AGENT);
                unsigned long long g = 0;
                while (__hip_atomic_load(c, __ATOMIC_RELAXED, __HIP_MEMORY_SCOPE_AGENT) < FUSED_GRID) {
                    __builtin_amdgcn_s_sleep(2);
                    if (++g > GUARD_SPINS) break;   // fail fast, not 600s
                }
            }
            __syncthreads();
        }

        // ---------------- eig phase (ALL blocks, redundant) ----------------
        const int cold  = (it == 0) ? 1 : 0;
        const int m_max = cold ? M_COLD : M_WARM;
        if (cold) {
            const float4* H4 = (const float4*)H;
            for (int k = tid; k < N2 / 4; k += 384) {
                int r = k / 24, c4 = (k - r * 24) * 4;
                float4 h = H4[k];
                float* f = &sm.mat[r * 97 + c4];
                f[0] = h.x; f[1] = h.y; f[2] = h.z; f[3] = h.w;
            }
        } else {
            // J/K written by other XCDs' atomics: read via agent atomic loads
            for (int i = tid; i < N2; i += 384) {
                float jj = __hip_atomic_load(&Jb[i], __ATOMIC_RELAXED, __HIP_MEMORY_SCOPE_AGENT);
                float kk = __hip_atomic_load(&Kb[i], __ATOMIC_RELAXED, __HIP_MEMORY_SCOPE_AGENT);
                int r = i / N, c = i - r * N;
                sm.mat[r * 97 + c] = H[i] + 2.f * jj - kk;
            }
        }
        if (tid < N) {
            float x;
            if (cold) {
                unsigned r = (unsigned)tid * 1103515245u + 12345u;
                r ^= r >> 13; r *= 2654435761u; r ^= r >> 16;
                x = (float)(r & 0xFFFFu) * (1.0f / 65536.0f) - 0.45f;
                sm.v4[tid] = 0.f;
            } else {
                x = sm.u_keep[tid];
                sm.v4[tid] = x;
            }
            sm.v0[tid] = x;
        }
        if (tid == 0) { sm.meff = m_max; sm.done = 0; sm.convl = 0; sm.beta[0] = 0.f; }
        __syncthreads();
        if (wv == 0) {   // normalize -> V[0]
            float x0 = sm.v0[lane];
            float x1 = (lane < 32) ? sm.v0[lane + 64] : 0.f;
            float a = x0 * x0 + x1 * x1;
            #pragma unroll
            for (int o = 32; o; o >>= 1) a += __shfl_xor(a, o);
            float ib = 1.0f / sqrtf(a);
            sm.V[0][lane] = x0 * ib;
            if (lane < 32) sm.V[0][lane + 64] = x1 * ib;
        }
        __syncthreads();

        const int mvi = tid >> 2, mvc = tid & 3;
        for (int j = 0; j < m_max; ++j) {
            if (sm.done) break;
            {   // t1 = A * V[j]
                const float* row = A + mvi * N + mvc * 24;
                const float* src = &sm.V[j][mvc * 24];
                float pp = 0.f;
                #pragma unroll
                for (int k = 0; k < 24; ++k) pp += row[k] * src[k];
                pp += __shfl_xor(pp, 1); pp += __shfl_xor(pp, 2);
                if (mvc == 0) sm.v1[mvi] = pp;
            }
            __syncthreads();
            {   // t2 = Fs * t1
                const float* row = &sm.mat[mvi * 97 + mvc * 24];
                float pp = 0.f;
                #pragma unroll
                for (int k = 0; k < 24; ++k) pp += row[k] * sm.v1[mvc * 24 + k];
                pp += __shfl_xor(pp, 1); pp += __shfl_xor(pp, 2);
                if (mvc == 0) sm.v2[mvi] = pp;
            }
            __syncthreads();
            {   // w = A * t2
                const float* row = A + mvi * N + mvc * 24;
                float pp = 0.f;
                #pragma unroll
                for (int k = 0; k < 24; ++k) pp += row[k] * sm.v2[mvc * 24 + k];
                pp += __shfl_xor(pp, 1); pp += __shfl_xor(pp, 2);
                if (mvc == 0) sm.v0[mvi] = pp;
            }
            __syncthreads();
            for (int k = wv; k <= j; k += 6) {   // dred[k] = <V[k], w>
                float a = sm.V[k][lane] * sm.v0[lane];
                if (lane < 32) a += sm.V[k][lane + 64] * sm.v0[lane + 64];
                #pragma unroll
                for (int o = 32; o; o >>= 1) a += __shfl_xor(a, o);
                if (lane == 0) { sm.dred[k] = a; if (k == j) sm.alpha[j] = a; }
            }
            __syncthreads();
            if (j + 1 == m_max) break;
            if (wv == 0) {   // orthogonalize, norm, V[j+1]
                float x0 = sm.v0[lane];
                float x1 = (lane < 32) ? sm.v0[lane + 64] : 0.f;
                for (int k = 0; k <= j; ++k) {
                    float d = sm.dred[k];
                    x0 -= d * sm.V[k][lane];
                    if (lane < 32) x1 -= d * sm.V[k][lane + 64];
                }
                float a = x0 * x0 + x1 * x1;
                #pragma unroll
                for (int o = 32; o; o >>= 1) a += __shfl_xor(a, o);
                float b = sqrtf(a);
                if (lane == 0) sm.beta[j + 1] = b;
                if (b < 1e-5f) {
                    if (lane == 0) { sm.meff = j + 1; sm.done = 1; }
                } else {
                    float ib = 1.0f / b;
                    sm.V[j + 1][lane] = x0 * ib;
                    if (lane < 32) sm.V[j + 1][lane + 64] = x1 * ib;
                }
            }
            __syncthreads();
        }
        __syncthreads();
        const int m = sm.meff;

        if (wv == 0) {   // bisection: smallest tridiag eigenvalue
            float lo_l = 3e38f, hid = 3e38f;
            if (lane < m) {
                float bl = (lane > 0) ? fabsf(sm.beta[lane]) : 0.f;
                float br = (lane + 1 < m) ? fabsf(sm.beta[lane + 1]) : 0.f;
                lo_l = sm.alpha[lane] - bl - br;
                hid  = sm.alpha[lane];
            }
            #pragma unroll
            for (int o = 32; o; o >>= 1) {
                lo_l = fminf(lo_l, __shfl_xor(lo_l, o));
                hid  = fminf(hid,  __shfl_xor(hid,  o));
            }
            float lo = lo_l - 1e-5f, hi = hid + 1e-5f;
            for (int round = 0; round < 4; ++round) {
                float x = lo + (hi - lo) * (float)(lane + 1) * (1.0f / 65.0f);
                int cnt = 0;
                float qq = sm.alpha[0] - x;
                if (qq < 0.f) cnt++;
                for (int i2 = 1; i2 < m; ++i2) {
                    if (fabsf(qq) < 1e-25f) qq = (qq < 0.f) ? -1e-25f : 1e-25f;
                    float bi = sm.beta[i2];
                    qq = (sm.alpha[i2] - x) - bi * bi / qq;
                    if (qq < 0.f) cnt++;
                }
                unsigned long long mask = __ballot(cnt >= 1);
                if (mask == 0ull) {
                    lo = lo + (hi - lo) * (64.0f / 65.0f);
                } else {
                    int f = __builtin_ctzll(mask);
                    float xf  = lo + (hi - lo) * (float)(f + 1) * (1.0f / 65.0f);
                    float xfm = lo + (hi - lo) * (float)(f)     * (1.0f / 65.0f);
                    hi = xf; lo = xfm;
                }
            }
            if (lane == 0) sm.scal[1] = 0.5f * (lo + hi);
        }
        __syncthreads();

        if (tid == 0) {   // fp64 inverse iteration, shift below lam_min
            if (m == 1) {
                sm.wsml[0] = 1.0f;
            } else {
                double lam = (double)sm.scal[1] - 1e-6;
                for (int pass = 0; pass < 2; ++pass) {
                    double b0 = (double)sm.alpha[0] - lam;
                    if (fabs(b0) < 1e-18) b0 = (b0 < 0.0) ? -1e-18 : 1e-18;
                    sm.cp[0] = (double)sm.beta[1] / b0;
                    sm.dp[0] = (pass ? (double)sm.wsml[0] : 1.0) / b0;
                    for (int i2 = 1; i2 < m; ++i2) {
                        double ai = (double)sm.beta[i2];
                        double md = ((double)sm.alpha[i2] - lam) - ai * sm.cp[i2 - 1];
                        if (fabs(md) < 1e-18) md = (md < 0.0) ? -1e-18 : 1e-18;
                        sm.cp[i2] = ((i2 + 1 < m) ? (double)sm.beta[i2 + 1] : 0.0) / md;
                        double rhs = pass ? (double)sm.wsml[i2] : 1.0;
                        sm.dp[i2] = (rhs - ai * sm.dp[i2 - 1]) / md;
                    }
                    for (int i2 = m - 2; i2 >= 0; --i2) sm.dp[i2] -= sm.cp[i2] * sm.dp[i2 + 1];
                    double nn = 0.0;
                    for (int i2 = 0; i2 < m; ++i2) nn += sm.dp[i2] * sm.dp[i2];
                    if (!(nn > 0.0) || isinf(nn)) {
                        for (int i2 = 0; i2 < m; ++i2) sm.wsml[i2] = (i2 == 0) ? 1.0f : 0.0f;
                    } else {
                        double inv = 1.0 / sqrt(nn);
                        for (int i2 = 0; i2 < m; ++i2) sm.wsml[i2] = (float)(sm.dp[i2] * inv);
                    }
                }
            }
        }
        __syncthreads();

        if (tid < N) {   // Ritz u = V^T wsml
            float acc = 0.f;
            for (int j = 0; j < m; ++j) acc += sm.wsml[j] * sm.V[j][tid];
            sm.v0[tid] = acc;
        }
        __syncthreads();
        if (wv == 0) {   // norm + sign-dot with uold
            float x0 = sm.v0[lane], x1 = (lane < 32) ? sm.v0[lane + 64] : 0.f;
            float u0 = sm.v4[lane], u1 = (lane < 32) ? sm.v4[lane + 64] : 0.f;
            float a = x0 * x0 + x1 * x1;
            float d = x0 * u0 + x1 * u1;
            #pragma unroll
            for (int o = 32; o; o >>= 1) { a += __shfl_xor(a, o); d += __shfl_xor(d, o); }
            if (lane == 0) { sm.scal[2] = sqrtf(a); sm.scal[3] = d; }
        }
        __syncthreads();
        {
            const float sgn = (!cold && sm.scal[3] < 0.f) ? -1.f : 1.f;
            if (tid < N) {
                float un = sgn * sm.v0[tid] / sm.scal[2];
                sm.v0[tid] = un;
                sm.u_keep[tid] = un;           // block-local warm start
                sm.v5[tid] = fabsf(un - sm.v4[tid]);
            }
        }
        __syncthreads();
        if (tid < N) {   // v = A @ u (block-local)
            const float* row = A + tid * N;
            float acc = 0.f;
            for (int k = 0; k < N; ++k) acc += row[k] * sm.v0[k];
            sm.v3[tid] = acc;
            sm.v_keep[tid] = acc;
        } else if (wv == 3) {   // conv reduce (identical in every block)
            float d0 = sm.v5[lane];
            if (lane < 32) d0 = fmaxf(d0, sm.v5[lane + 64]);
            #pragma unroll
            for (int o = 32; o; o >>= 1) d0 = fmaxf(d0, __shfl_xor(d0, o));
            if (lane == 0 && !cold && d0 < CONV_TOL) sm.convl = 1;
        }
        __syncthreads();
        {   // energy rows: tmp[i] = sum_k (F+H)[i,k] vn[k]
            const float* frow = &sm.mat[mvi * 97 + mvc * 24];
            const float* hrow = H + mvi * N + mvc * 24;
            float pp = 0.f;
            #pragma unroll
            for (int k = 0; k < 24; ++k) pp += (frow[k] + hrow[k]) * sm.v3[mvc * 24 + k];
            pp += __shfl_xor(pp, 1); pp += __shfl_xor(pp, 2);
            if (mvc == 0) sm.v0[mvi] = pp;
        }
        __syncthreads();
        if (bid == 0 && wv == 0) {
            float e = sm.v3[lane] * sm.v0[lane];
            if (lane < 32) e += sm.v3[lane + 64] * sm.v0[lane + 64];
            #pragma unroll
            for (int o = 32; o; o >>= 1) e += __shfl_xor(e, o);
            if (lane == 0) out[0] = e + Enuc[0];
        }
        if (sm.convl) break;   // identical in every block -> uniform exit
    }
}

// ===========================================================================
// FALLBACK path (round-14 proven kernels) if cooperative launch fails.
// ===========================================================================
template <int MODE>
__global__ __launch_bounds__(256)
void k_contract_fb(const float* __restrict__ G, const unsigned short* __restrict__ Gb,
                   const float* __restrict__ v,
                   float* __restrict__ J, float* __restrict__ K,
                   const int* __restrict__ conv)
{
    if (*conv) return;
    __shared__ float Ms[N * 97];
    __shared__ float vs[N];
    __shared__ float rsh[N];
    __shared__ float csh[N];
    const int tid = threadIdx.x;
    if (tid < N) vs[tid] = v[tid];
    for (int pr = blockIdx.x; pr < NPAIR_SYM; pr += (int)gridDim.x) {
        int p, q;
        decode_pq(pr, p, q);
        __syncthreads();
        if (MODE == 2) {
            const uint4* Gb4 = (const uint4*)(Gb + (size_t)pr * N2);
            for (int i = tid; i < N2 / 8; i += 256) {
                uint4 u = Gb4[i];
                int r = i / 12, s0 = (i - r * 12) * 8;
                float* dst = &Ms[r * 97 + s0];
                dst[0] = bf2f(u.x & 0xFFFFu); dst[1] = bf2f(u.x >> 16);
                dst[2] = bf2f(u.y & 0xFFFFu); dst[3] = bf2f(u.y >> 16);
                dst[4] = bf2f(u.z & 0xFFFFu); dst[5] = bf2f(u.z >> 16);
                dst[6] = bf2f(u.w & 0xFFFFu); dst[7] = bf2f(u.w >> 16);
            }
        } else {
            const float4* G4 = (const float4*)(G + (size_t)(p * N + q) * N2);
            for (int k = tid; k < N2 / 4; k += 256) {
                float4 f = G4[k];
                int r = k / 24, s4 = (k - r * 24) * 4;
                float* dst = &Ms[r * 97 + s4];
                dst[0] = f.x; dst[1] = f.y; dst[2] = f.z; dst[3] = f.w;
            }
        }
        __syncthreads();
        if (tid < N) {
            const float* row = &Ms[tid * 97];
            float acc = 0.f;
            #pragma unroll 8
            for (int s = 0; s < N; ++s) acc += row[s] * vs[s];
            atomicAdd(&K[p * N + tid], vs[q] * acc);
            rsh[tid] = acc * vs[tid];
        } else if (tid < 2 * N && p != q) {
            const int s = tid - N;
            float acc = 0.f;
            #pragma unroll 8
            for (int r = 0; r < N; ++r) acc += Ms[r * 97 + s] * vs[r];
            atomicAdd(&K[q * N + s], vs[p] * acc);
            csh[s] = acc * vs[s];
        }
        __syncthreads();
        const int lane = tid & 63, wv = tid >> 6;
        if (wv == 0) {
            float a = rsh[lane];
            if (lane < 32) a += rsh[lane + 64];
            #pragma unroll
            for (int o = 32; o; o >>= 1) a += __shfl_xor(a, o);
            if (lane == 0) J[p * N + q] = a;
        } else if (wv == 1 && p != q) {
            float a = csh[lane];
            if (lane < 32) a += csh[lane + 64];
            #pragma unroll
            for (int o = 32; o; o >>= 1) a += __shfl_xor(a, o);
            if (lane == 0) J[q * N + p] = a;
        }
    }
}

__global__ __launch_bounds__(384)
void k_eig_fb(const float* __restrict__ J, const float* __restrict__ K,
              const float* __restrict__ A, const float* __restrict__ H,
              const float* __restrict__ Enuc,
              float* __restrict__ v_ws, float* __restrict__ u_ws,
              float* __restrict__ jk, float* __restrict__ out,
              int cold, int m_max, int* __restrict__ conv)
{
    if (!cold && *conv) return;
    __shared__ SMem sm;
    const int tid  = threadIdx.x;
    const int lane = tid & 63;
    const int wv   = tid >> 6;
    if (cold && tid == 0) atomicExch(conv, 0);
    {
        const float4* H4 = (const float4*)H;
        const float4* J4 = (const float4*)J;
        const float4* K4 = (const float4*)K;
        for (int k = tid; k < N2 / 4; k += 384) {
            int r = k / 24, c4 = (k - r * 24) * 4;
            float4 h = H4[k];
            float* f = &sm.mat[r * 97 + c4];
            if (cold) { f[0] = h.x; f[1] = h.y; f[2] = h.z; f[3] = h.w; }
            else {
                float4 jj = J4[k], kk = K4[k];
                f[0] = h.x + 2.f * jj.x - kk.x;
                f[1] = h.y + 2.f * jj.y - kk.y;
                f[2] = h.z + 2.f * jj.z - kk.z;
                f[3] = h.w + 2.f * jj.w - kk.w;
            }
        }
    }
    if (tid < N) {
        float x;
        if (cold) {
            unsigned r = (unsigned)tid * 1103515245u + 12345u;
            r ^= r >> 13; r *= 2654435761u; r ^= r >> 16;
            x = (float)(r & 0xFFFFu) * (1.0f / 65536.0f) - 0.45f;
            sm.v4[tid] = 0.f;
        } else { x = u_ws[tid]; sm.v4[tid] = x; }
        sm.v0[tid] = x;
    }
    if (tid == 0) { sm.meff = m_max; sm.done = 0; sm.beta[0] = 0.f; }
    __syncthreads();
    for (int i = tid; i < 2 * N2; i += 384) jk[i] = 0.f;
    if (wv == 0) {
        float x0 = sm.v0[lane];
        float x1 = (lane < 32) ? sm.v0[lane + 64] : 0.f;
        float a = x0 * x0 + x1 * x1;
        #pragma unroll
        for (int o = 32; o; o >>= 1) a += __shfl_xor(a, o);
        float ib = 1.0f / sqrtf(a);
        sm.V[0][lane] = x0 * ib;
        if (lane < 32) sm.V[0][lane + 64] = x1 * ib;
    }
    __syncthreads();
    const int mvi = tid >> 2, mvc = tid & 3;
    for (int j = 0; j < m_max; ++j) {
        if (sm.done) break;
        {
            const float* row = A + mvi * N + mvc * 24;
            const float* src = &sm.V[j][mvc * 24];
            float pp = 0.f;
            #pragma unroll
            for (int k = 0; k < 24; ++k) pp += row[k] * src[k];
            pp += __shfl_xor(pp, 1); pp += __shfl_xor(pp, 2);
            if (mvc == 0) sm.v1[mvi] = pp;
        }
        __syncthreads();
        {
            const float* row = &sm.mat[mvi * 97 + mvc * 24];
            float pp = 0.f;
            #pragma unroll
            for (int k = 0; k < 24; ++k) pp += row[k] * sm.v1[mvc * 24 + k];
            pp += __shfl_xor(pp, 1); pp += __shfl_xor(pp, 2);
            if (mvc == 0) sm.v2[mvi] = pp;
        }
        __syncthreads();
        {
            const float* row = A + mvi * N + mvc * 24;
            float pp = 0.f;
            #pragma unroll
            for (int k = 0; k < 24; ++k) pp += row[k] * sm.v2[mvc * 24 + k];
            pp += __shfl_xor(pp, 1); pp += __shfl_xor(pp, 2);
            if (mvc == 0) sm.v0[mvi] = pp;
        }
        __syncthreads();
        for (int k = wv; k <= j; k += 6) {
            float a = sm.V[k][lane] * sm.v0[lane];
            if (lane < 32) a += sm.V[k][lane + 64] * sm.v0[lane + 64];
            #pragma unroll
            for (int o = 32; o; o >>= 1) a += __shfl_xor(a, o);
            if (lane == 0) { sm.dred[k] = a; if (k == j) sm.alpha[j] = a; }
        }
        __syncthreads();
        if (j + 1 == m_max) break;
        if (wv == 0) {
            float x0 = sm.v0[lane];
            float x1 = (lane < 32) ? sm.v0[lane + 64] : 0.f;
            for (int k = 0; k <= j; ++k) {
                float d = sm.dred[k];
                x0 -= d * sm.V[k][lane];
                if (lane < 32) x1 -= d * sm.V[k][lane + 64];
            }
            float a = x0 * x0 + x1 * x1;
            #pragma unroll
            for (int o = 32; o; o >>= 1) a += __shfl_xor(a, o);
            float b = sqrtf(a);
            if (lane == 0) sm.beta[j + 1] = b;
            if (b < 1e-5f) { if (lane == 0) { sm.meff = j + 1; sm.done = 1; } }
            else {
                float ib = 1.0f / b;
                sm.V[j + 1][lane] = x0 * ib;
                if (lane < 32) sm.V[j + 1][lane + 64] = x1 * ib;
            }
        }
        __syncthreads();
    }
    __syncthreads();
    const int m = sm.meff;
    if (wv == 0) {
        float lo_l = 3e38f, hid = 3e38f;
        if (lane < m) {
            float bl = (lane > 0) ? fabsf(sm.beta[lane]) : 0.f;
            float br = (lane + 1 < m) ? fabsf(sm.beta[lane + 1]) : 0.f;
            lo_l = sm.alpha[lane] - bl - br;
            hid  = sm.alpha[lane];
        }
        #pragma unroll
        for (int o = 32; o; o >>= 1) {
            lo_l = fminf(lo_l, __shfl_xor(lo_l, o));
            hid  = fminf(hid,  __shfl_xor(hid,  o));
        }
        float lo = lo_l - 1e-5f, hi = hid + 1e-5f;
        for (int round = 0; round < 4; ++round) {
            float x = lo + (hi - lo) * (float)(lane + 1) * (1.0f / 65.0f);
            int cnt = 0;
            float qq = sm.alpha[0] - x;
            if (qq < 0.f) cnt++;
            for (int i2 = 1; i2 < m; ++i2) {
                if (fabsf(qq) < 1e-25f) qq = (qq < 0.f) ? -1e-25f : 1e-25f;
                float bi = sm.beta[i2];
                qq = (sm.alpha[i2] - x) - bi * bi / qq;
                if (qq < 0.f) cnt++;
            }
            unsigned long long mask = __ballot(cnt >= 1);
            if (mask == 0ull) lo = lo + (hi - lo) * (64.0f / 65.0f);
            else {
                int f = __builtin_ctzll(mask);
                float xf  = lo + (hi - lo) * (float)(f + 1) * (1.0f / 65.0f);
                float xfm = lo + (hi - lo) * (float)(f)     * (1.0f / 65.0f);
                hi = xf; lo = xfm;
            }
        }
        if (lane == 0) sm.scal[1] = 0.5f * (lo + hi);
    }
    __syncthreads();
    if (tid == 0) {
        if (m == 1) sm.wsml[0] = 1.0f;
        else {
            double lam = (double)sm.scal[1] - 1e-6;
            for (int pass = 0; pass < 2; ++pass) {
                double b0 = (double)sm.alpha[0] - lam;
                if (fabs(b0) < 1e-18) b0 = (b0 < 0.0) ? -1e-18 : 1e-18;
                sm.cp[0] = (double)sm.beta[1] / b0;
                sm.dp[0] = (pass ? (double)sm.wsml[0] : 1.0) / b0;
                for (int i2 = 1; i2 < m; ++i2) {
                    double ai = (double)sm.beta[i2];
                    double md = ((double)sm.alpha[i2] - lam) - ai * sm.cp[i2 - 1];
                    if (fabs(md) < 1e-18) md = (md < 0.0) ? -1e-18 : 1e-18;
                    sm.cp[i2] = ((i2 + 1 < m) ? (double)sm.beta[i2 + 1] : 0.0) / md;
                    double rhs = pass ? (double)sm.wsml[i2] : 1.0;
                    sm.dp[i2] = (rhs - ai * sm.dp[i2 - 1]) / md;
                }
                for (int i2 = m - 2; i2 >= 0; --i2) sm.dp[i2] -= sm.cp[i2] * sm.dp[i2 + 1];
                double nn = 0.0;
                for (int i2 = 0; i2 < m; ++i2) nn += sm.dp[i2] * sm.dp[i2];
                if (!(nn > 0.0) || isinf(nn)) {
                    for (int i2 = 0; i2 < m; ++i2) sm.wsml[i2] = (i2 == 0) ? 1.0f : 0.0f;
                } else {
                    double inv = 1.0 / sqrt(nn);
                    for (int i2 = 0; i2 < m; ++i2) sm.wsml[i2] = (float)(sm.dp[i2] * inv);
                }
            }
        }
    }
    __syncthreads();
    if (tid < N) {
        float acc = 0.f;
        for (int j = 0; j < m; ++j) acc += sm.wsml[j] * sm.V[j][tid];
        sm.v0[tid] = acc;
    }
    __syncthreads();
    if (wv == 0) {
        float x0 = sm.v0[lane], x1 = (lane < 32) ? sm.v0[lane + 64] : 0.f;
        float u0 = sm.v4[lane], u1 = (lane < 32) ? sm.v4[lane + 64] : 0.f;
        float a = x0 * x0 + x1 * x1;
        float d = x0 * u0 + x1 * u1;
        #pragma unroll
        for (int o = 32; o; o >>= 1) { a += __shfl_xor(a, o); d += __shfl_xor(d, o); }
        if (lane == 0) { sm.scal[2] = sqrtf(a); sm.scal[3] = d; }
    }
    __syncthreads();
    {
        const float sgn = (!cold && sm.scal[3] < 0.f) ? -1.f : 1.f;
        if (tid < N) {
            float un = sgn * sm.v0[tid] / sm.scal[2];
            sm.v0[tid] = un;
            u_ws[tid] = un;
            sm.v5[tid] = fabsf(un - sm.v4[tid]);
        }
    }
    __syncthreads();
    if (tid < N) {
        const float* row = A + tid * N;
        float acc = 0.f;
        for (int k = 0; k < N; ++k) acc += row[k] * sm.v0[k];
        sm.v3[tid] = acc;
        v_ws[tid] = acc;
    } else if (wv == 3) {
        float d0 = sm.v5[lane];
        if (lane < 32) d0 = fmaxf(d0, sm.v5[lane + 64]);
        #pragma unroll
        for (int o = 32; o; o >>= 1) d0 = fmaxf(d0, __shfl_xor(d0, o));
        if (lane == 0 && !cold && d0 < CONV_TOL) atomicExch(conv, 1);
    }
    __syncthreads();
    {
        const float* frow = &sm.mat[mvi * 97 + mvc * 24];
        const float* hrow = H + mvi * N + mvc * 24;
        float pp = 0.f;
        #pragma unroll
        for (int k = 0; k < 24; ++k) pp += (frow[k] + hrow[k]) * sm.v3[mvc * 24 + k];
        pp += __shfl_xor(pp, 1); pp += __shfl_xor(pp, 2);
        if (mvc == 0) sm.v0[mvi] = pp;
    }
    __syncthreads();
    if (wv == 0) {
        float e = sm.v3[lane] * sm.v0[lane];
        if (lane < 32) e += sm.v3[lane + 64] * sm.v0[lane + 64];
        #pragma unroll
        for (int o = 32; o; o >>= 1) e += __shfl_xor(e, o);
        if (lane == 0) out[0] = e + Enuc[0];
    }
}

// ---------------------------------------------------------------------------
extern "C" void kernel_launch(void* const* d_in, const int* in_sizes, int n_in,
                              void* d_out, int out_size, void* d_ws, size_t ws_size,
                              hipStream_t stream)
{
    (void)in_sizes; (void)n_in; (void)out_size;
    const float* H    = (const float*)d_in[1];
    const float* A    = (const float*)d_in[2];
    const float* G    = (const float*)d_in[3];
    const float* Enuc = (const float*)d_in[4];
    float* out = (float*)d_out;
    float* ws  = (float*)d_ws;
    int*   ctr = (int*)d_ws;
    int*  conv = ctr + OFFI_CONV;
    float* jk  = ws + OFF_JK;
    float* v   = ws + OFF_V;
    float* u   = ws + OFF_U;
    unsigned short* Gb = (unsigned short*)(ws + OFF_GB);
    int bf16i = (ws_size >= NEED_BF16_BYTES) ? 1 : 0;

    k_prep<<<2048, 256, 0, stream>>>(ctr, jk, G, Gb, bf16i);

    const unsigned short* Gbc = Gb;
    void* kargs[] = { (void*)&G, (void*)&Gbc, (void*)&A, (void*)&H, (void*)&Enuc,
                      (void*)&jk, (void*)&ctr, (void*)&out, (void*)&bf16i };
    hipError_t err = hipLaunchCooperativeKernel((const void*)k_scf,
                                                dim3(FUSED_GRID), dim3(384),
                                                kargs, 0, stream);
    if (err == hipSuccess) return;
    (void)hipGetLastError();   // clear error state, take proven fallback path

    float* Jb = jk;            // buffer 0 (zeroed by k_prep; re-zeroed by eig_fb)
    float* Kb = jk + N2;
    for (int it = 0; it < MAXIT; ++it) {
        if (it > 0) {
            if (bf16i)
                k_contract_fb<2><<<FB_GRID, 256, 0, stream>>>(G, Gb, v, Jb, Kb, conv);
            else
                k_contract_fb<0><<<FB_GRID, 256, 0, stream>>>(G, Gb, v, Jb, Kb, conv);
        }
        k_eig_fb<<<1, 384, 0, stream>>>(Jb, Kb, A, H, Enuc, v, u, Jb, out,
                                        it == 0 ? 1 : 0,
                                        it == 0 ? M_COLD : M_WARM,
                                        conv);
    }
}

// Round 17
// 325.657 us; speedup vs baseline: 5149.2634x; 5149.2634x over previous
//
#include <hip/hip_runtime.h>
#include <math.h>

#define N   96
#define N2  9216
#define NPAIR_SYM 4656     // 96*97/2 (p<=q) pair-blocks of G

#define M_COLD 16
#define M_WARM 5
#define CONV_TOL 1e-2f
#define FUSED_GRID 512     // 2/CU co-resident; PROVEN (r12/r14). 768 broke co-residency (r16).
#define FB_GRID 1024       // fallback contract grid
#define MAXIT 20
#define NBAR (MAXIT - 1)
#define GUARD_SPINS 3000000ull   // ~150ms: fail fast instead of 600s timeout

// ---- d_ws layout ----
// ints (from base):
#define OFFI_CTR  0                    // NBAR counters, stride 16 ints (64B each)
#define OFFI_CONV (NBAR * 16)          // fallback conv flag
// floats (from base):
#define OFF_JK    512                  // per-iteration J/K buffers: it t uses [(t-1)*2*N2, +2*N2)
#define JKFLOATS  (NBAR * 2 * N2)
#define OFF_V     (OFF_JK + JKFLOATS)  // fallback v (96)
#define OFF_U     (OFF_V + 128)        // fallback u (96)
#define OFF_GB    (OFF_U + 128)        // bf16 G-half: 4656*9216 ushorts
#define NEED_BF16_BYTES ((size_t)OFF_GB * 4 + (size_t)NPAIR_SYM * N2 * 2)

__device__ __forceinline__ unsigned short f2bf(float x) {
    unsigned u = __float_as_uint(x);
    unsigned r = (u + 0x7FFFu + ((u >> 16) & 1u)) >> 16;
    return (unsigned short)r;
}
__device__ __forceinline__ float bf2f(unsigned h) {
    return __uint_as_float(h << 16);
}
__device__ __forceinline__ void decode_pq(int pr, int& p_, int& q_) {
    int p = (int)((193.0 - sqrt(37249.0 - 8.0 * (double)pr)) * 0.5);
    if (p > 95) p = 95;
    if (p < 0) p = 0;
    while (p * 96 - p * (p - 1) / 2 > pr) --p;
    while ((p + 1) * 96 - (p + 1) * p / 2 <= pr) ++p;
    p_ = p;
    q_ = p + (pr - (p * 96 - p * (p - 1) / 2));
}

struct SMem {
    float mat[N * 97];          // contract: Ms ; eig: Fs
    float V[M_COLD][N];
    float v0[N], v1[N], v2[N], v3[N], v4[N], v5[N];
    float u_keep[N], v_keep[N]; // persistent across iterations (block-local)
    float alpha[M_COLD + 1], beta[M_COLD + 1], dred[M_COLD], wsml[M_COLD];
    double cp[M_COLD], dp[M_COLD];
    float scal[4];
    int meff, done, convl;
};

// ===========================================================================
// k_prep: zero barrier counters + conv flag + J/K buffers, AND convert the
// p<=q half of G to bf16 (disjoint writes; no ordering needed). One dispatch.
// Runs every kernel_launch -> graph replays always start from clean state.
// Dispatch-end L2 writeback makes Gb globally visible to k_scf.
// ===========================================================================
__global__ __launch_bounds__(256)
void k_prep(int* __restrict__ ctr, float* __restrict__ jk,
            const float* __restrict__ G, unsigned short* __restrict__ Gb,
            int doconv)
{
    const int gtid = blockIdx.x * blockDim.x + threadIdx.x;
    const int nth  = gridDim.x * blockDim.x;
    for (int i = gtid; i < NBAR * 16 + 16; i += nth) ctr[i] = 0;
    for (int i = gtid; i < JKFLOATS; i += nth) jk[i] = 0.f;
    if (doconv) {
        const int tid = threadIdx.x;
        for (int pr = blockIdx.x; pr < NPAIR_SYM; pr += (int)gridDim.x) {
            int p, q;
            decode_pq(pr, p, q);
            const float4* G4 = (const float4*)(G + (size_t)(p * N + q) * N2);
            uint2* Gb2 = (uint2*)(Gb + (size_t)pr * N2);
            for (int k = tid; k < N2 / 4; k += 256) {
                float4 f = G4[k];
                uint2 o;
                o.x = (unsigned)f2bf(f.x) | ((unsigned)f2bf(f.y) << 16);
                o.y = (unsigned)f2bf(f.z) | ((unsigned)f2bf(f.w) << 16);
                Gb2[k] = o;
            }
        }
    }
}

// ===========================================================================
// k_scf: persistent fused SCF, NO grid.sync (round-12/14 proven skeleton).
// Per iteration t>=1:
//   [all blocks] contract own pair-blocks (read pre-converted bf16 Gb)
//     -> atomicAdd into fresh J/K[t]
//   flush-free barrier: counter[t-1] atomicAdd + relaxed spin (data crosses
//     blocks ONLY via device-scope atomics; J/K read back via agent loads)
//   [ALL blocks, redundant] F=H+2J-K in LDS; warm Lanczos (Fp x = A(F(Ax)));
//     bisection; fp64 inverse iter; Ritz; u,v kept block-local;
//     identical inputs -> identical result in every block -> uniform break.
// ===========================================================================
__global__ __launch_bounds__(384)
void k_scf(const float* __restrict__ G, const unsigned short* __restrict__ Gb,
           const float* __restrict__ A, const float* __restrict__ H,
           const float* __restrict__ Enuc,
           float* __restrict__ jk, int* __restrict__ ctr,
           float* __restrict__ out, int bf16ok)
{
    __shared__ SMem sm;
    const int tid  = threadIdx.x;
    const int bid  = blockIdx.x;
    const int lane = tid & 63;
    const int wv   = tid >> 6;

    for (int it = 0; it < MAXIT; ++it) {
        float* Jb = jk + (size_t)(it > 0 ? it - 1 : 0) * 2 * N2;
        float* Kb = Jb + N2;

        // ---------------- contract phase ----------------
        if (it > 0) {
            for (int pr = bid; pr < NPAIR_SYM; pr += FUSED_GRID) {
                int p, q;
                decode_pq(pr, p, q);
                __syncthreads();   // sm.mat free; v_keep visible
                if (bf16ok) {
                    const uint4* Gb4 = (const uint4*)(Gb + (size_t)pr * N2);
                    for (int i = tid; i < N2 / 8; i += 384) {
                        uint4 u = Gb4[i];
                        int r = i / 12, s0 = (i - r * 12) * 8;
                        float* dst = &sm.mat[r * 97 + s0];
                        dst[0] = bf2f(u.x & 0xFFFFu); dst[1] = bf2f(u.x >> 16);
                        dst[2] = bf2f(u.y & 0xFFFFu); dst[3] = bf2f(u.y >> 16);
                        dst[4] = bf2f(u.z & 0xFFFFu); dst[5] = bf2f(u.z >> 16);
                        dst[6] = bf2f(u.w & 0xFFFFu); dst[7] = bf2f(u.w >> 16);
                    }
                } else {
                    const float4* G4 = (const float4*)(G + (size_t)(p * N + q) * N2);
                    for (int k = tid; k < N2 / 4; k += 384) {
                        float4 f = G4[k];
                        int r = k / 24, s4 = (k - r * 24) * 4;
                        float* dst = &sm.mat[r * 97 + s4];
                        dst[0] = f.x; dst[1] = f.y; dst[2] = f.z; dst[3] = f.w;
                    }
                }
                __syncthreads();
                if (tid < N) {                 // row dot
                    const float* row = &sm.mat[tid * 97];
                    float acc = 0.f;
                    #pragma unroll 8
                    for (int s = 0; s < N; ++s) acc += row[s] * sm.v_keep[s];
                    atomicAdd(&Kb[p * N + tid], sm.v_keep[q] * acc);
                    sm.v1[tid] = acc * sm.v_keep[tid];
                } else if (tid < 2 * N && p != q) {  // col dot
                    const int s = tid - N;
                    float acc = 0.f;
                    #pragma unroll 8
                    for (int r = 0; r < N; ++r) acc += sm.mat[r * 97 + s] * sm.v_keep[r];
                    atomicAdd(&Kb[q * N + s], sm.v_keep[p] * acc);
                    sm.v2[s] = acc * sm.v_keep[s];
                }
                __syncthreads();
                if (wv == 0) {                 // J[p,q]
                    float a = sm.v1[lane];
                    if (lane < 32) a += sm.v1[lane + 64];
                    #pragma unroll
                    for (int o = 32; o; o >>= 1) a += __shfl_xor(a, o);
                    if (lane == 0) atomicAdd(&Jb[p * N + q], a);
                } else if (wv == 1 && p != q) { // J[q,p]
                    float a = sm.v2[lane];
                    if (lane < 32) a += sm.v2[lane + 64];
                    #pragma unroll
                    for (int o = 32; o; o >>= 1) a += __shfl_xor(a, o);
                    if (lane == 0) atomicAdd(&Jb[q * N + p], a);
                }
            }
            __syncthreads();   // drains outstanding atomics (vmcnt before s_barrier)
            // ---- flush-free barrier on counter[it-1] ----
            if (tid == 0) {
                int* c = ctr + (size_t)(it - 1) * 16;
                __hip_atomic_fetch_add(c, 1, __ATOMIC_RELEASE, __HIP_MEMORY_SCOPE_AGENT);
                unsigned long long g = 0;
                while (__hip_atomic_load(c, __ATOMIC_RELAXED, __HIP_MEMORY_SCOPE_AGENT) < FUSED_GRID) {
                    __builtin_amdgcn_s_sleep(2);
                    if (++g > GUARD_SPINS) break;   // fail fast, not 600s
                }
            }
            __syncthreads();
        }

        // ---------------- eig phase (ALL blocks, redundant) ----------------
        const int cold  = (it == 0) ? 1 : 0;
        const int m_max = cold ? M_COLD : M_WARM;
        if (cold) {
            const float4* H4 = (const float4*)H;
            for (int k = tid; k < N2 / 4; k += 384) {
                int r = k / 24, c4 = (k - r * 24) * 4;
                float4 h = H4[k];
                float* f = &sm.mat[r * 97 + c4];
                f[0] = h.x; f[1] = h.y; f[2] = h.z; f[3] = h.w;
            }
        } else {
            // J/K written by other XCDs' atomics: read via agent atomic loads
            for (int i = tid; i < N2; i += 384) {
                float jj = __hip_atomic_load(&Jb[i], __ATOMIC_RELAXED, __HIP_MEMORY_SCOPE_AGENT);
                float kk = __hip_atomic_load(&Kb[i], __ATOMIC_RELAXED, __HIP_MEMORY_SCOPE_AGENT);
                int r = i / N, c = i - r * N;
                sm.mat[r * 97 + c] = H[i] + 2.f * jj - kk;
            }
        }
        if (tid < N) {
            float x;
            if (cold) {
                unsigned r = (unsigned)tid * 1103515245u + 12345u;
                r ^= r >> 13; r *= 2654435761u; r ^= r >> 16;
                x = (float)(r & 0xFFFFu) * (1.0f / 65536.0f) - 0.45f;
                sm.v4[tid] = 0.f;
            } else {
                x = sm.u_keep[tid];
                sm.v4[tid] = x;
            }
            sm.v0[tid] = x;
        }
        if (tid == 0) { sm.meff = m_max; sm.done = 0; sm.convl = 0; sm.beta[0] = 0.f; }
        __syncthreads();
        if (wv == 0) {   // normalize -> V[0]
            float x0 = sm.v0[lane];
            float x1 = (lane < 32) ? sm.v0[lane + 64] : 0.f;
            float a = x0 * x0 + x1 * x1;
            #pragma unroll
            for (int o = 32; o; o >>= 1) a += __shfl_xor(a, o);
            float ib = 1.0f / sqrtf(a);
            sm.V[0][lane] = x0 * ib;
            if (lane < 32) sm.V[0][lane + 64] = x1 * ib;
        }
        __syncthreads();

        const int mvi = tid >> 2, mvc = tid & 3;
        for (int j = 0; j < m_max; ++j) {
            if (sm.done) break;
            {   // t1 = A * V[j]
                const float* row = A + mvi * N + mvc * 24;
                const float* src = &sm.V[j][mvc * 24];
                float pp = 0.f;
                #pragma unroll
                for (int k = 0; k < 24; ++k) pp += row[k] * src[k];
                pp += __shfl_xor(pp, 1); pp += __shfl_xor(pp, 2);
                if (mvc == 0) sm.v1[mvi] = pp;
            }
            __syncthreads();
            {   // t2 = Fs * t1
                const float* row = &sm.mat[mvi * 97 + mvc * 24];
                float pp = 0.f;
                #pragma unroll
                for (int k = 0; k < 24; ++k) pp += row[k] * sm.v1[mvc * 24 + k];
                pp += __shfl_xor(pp, 1); pp += __shfl_xor(pp, 2);
                if (mvc == 0) sm.v2[mvi] = pp;
            }
            __syncthreads();
            {   // w = A * t2
                const float* row = A + mvi * N + mvc * 24;
                float pp = 0.f;
                #pragma unroll
                for (int k = 0; k < 24; ++k) pp += row[k] * sm.v2[mvc * 24 + k];
                pp += __shfl_xor(pp, 1); pp += __shfl_xor(pp, 2);
                if (mvc == 0) sm.v0[mvi] = pp;
            }
            __syncthreads();
            for (int k = wv; k <= j; k += 6) {   // dred[k] = <V[k], w>
                float a = sm.V[k][lane] * sm.v0[lane];
                if (lane < 32) a += sm.V[k][lane + 64] * sm.v0[lane + 64];
                #pragma unroll
                for (int o = 32; o; o >>= 1) a += __shfl_xor(a, o);
                if (lane == 0) { sm.dred[k] = a; if (k == j) sm.alpha[j] = a; }
            }
            __syncthreads();
            if (j + 1 == m_max) break;
            if (wv == 0) {   // orthogonalize, norm, V[j+1]
                float x0 = sm.v0[lane];
                float x1 = (lane < 32) ? sm.v0[lane + 64] : 0.f;
                for (int k = 0; k <= j; ++k) {
                    float d = sm.dred[k];
                    x0 -= d * sm.V[k][lane];
                    if (lane < 32) x1 -= d * sm.V[k][lane + 64];
                }
                float a = x0 * x0 + x1 * x1;
                #pragma unroll
                for (int o = 32; o; o >>= 1) a += __shfl_xor(a, o);
                float b = sqrtf(a);
                if (lane == 0) sm.beta[j + 1] = b;
                if (b < 1e-5f) {
                    if (lane == 0) { sm.meff = j + 1; sm.done = 1; }
                } else {
                    float ib = 1.0f / b;
                    sm.V[j + 1][lane] = x0 * ib;
                    if (lane < 32) sm.V[j + 1][lane + 64] = x1 * ib;
                }
            }
            __syncthreads();
        }
        __syncthreads();
        const int m = sm.meff;

        if (wv == 0) {   // bisection: smallest tridiag eigenvalue
            float lo_l = 3e38f, hid = 3e38f;
            if (lane < m) {
                float bl = (lane > 0) ? fabsf(sm.beta[lane]) : 0.f;
                float br = (lane + 1 < m) ? fabsf(sm.beta[lane + 1]) : 0.f;
                lo_l = sm.alpha[lane] - bl - br;
                hid  = sm.alpha[lane];
            }
            #pragma unroll
            for (int o = 32; o; o >>= 1) {
                lo_l = fminf(lo_l, __shfl_xor(lo_l, o));
                hid  = fminf(hid,  __shfl_xor(hid,  o));
            }
            float lo = lo_l - 1e-5f, hi = hid + 1e-5f;
            for (int round = 0; round < 4; ++round) {
                float x = lo + (hi - lo) * (float)(lane + 1) * (1.0f / 65.0f);
                int cnt = 0;
                float qq = sm.alpha[0] - x;
                if (qq < 0.f) cnt++;
                for (int i2 = 1; i2 < m; ++i2) {
                    if (fabsf(qq) < 1e-25f) qq = (qq < 0.f) ? -1e-25f : 1e-25f;
                    float bi = sm.beta[i2];
                    qq = (sm.alpha[i2] - x) - bi * bi / qq;
                    if (qq < 0.f) cnt++;
                }
                unsigned long long mask = __ballot(cnt >= 1);
                if (mask == 0ull) {
                    lo = lo + (hi - lo) * (64.0f / 65.0f);
                } else {
                    int f = __builtin_ctzll(mask);
                    float xf  = lo + (hi - lo) * (float)(f + 1) * (1.0f / 65.0f);
                    float xfm = lo + (hi - lo) * (float)(f)     * (1.0f / 65.0f);
                    hi = xf; lo = xfm;
                }
            }
            if (lane == 0) sm.scal[1] = 0.5f * (lo + hi);
        }
        __syncthreads();

        if (tid == 0) {   // fp64 inverse iteration, shift below lam_min
            if (m == 1) {
                sm.wsml[0] = 1.0f;
            } else {
                double lam = (double)sm.scal[1] - 1e-6;
                for (int pass = 0; pass < 2; ++pass) {
                    double b0 = (double)sm.alpha[0] - lam;
                    if (fabs(b0) < 1e-18) b0 = (b0 < 0.0) ? -1e-18 : 1e-18;
                    sm.cp[0] = (double)sm.beta[1] / b0;
                    sm.dp[0] = (pass ? (double)sm.wsml[0] : 1.0) / b0;
                    for (int i2 = 1; i2 < m; ++i2) {
                        double ai = (double)sm.beta[i2];
                        double md = ((double)sm.alpha[i2] - lam) - ai * sm.cp[i2 - 1];
                        if (fabs(md) < 1e-18) md = (md < 0.0) ? -1e-18 : 1e-18;
                        sm.cp[i2] = ((i2 + 1 < m) ? (double)sm.beta[i2 + 1] : 0.0) / md;
                        double rhs = pass ? (double)sm.wsml[i2] : 1.0;
                        sm.dp[i2] = (rhs - ai * sm.dp[i2 - 1]) / md;
                    }
                    for (int i2 = m - 2; i2 >= 0; --i2) sm.dp[i2] -= sm.cp[i2] * sm.dp[i2 + 1];
                    double nn = 0.0;
                    for (int i2 = 0; i2 < m; ++i2) nn += sm.dp[i2] * sm.dp[i2];
                    if (!(nn > 0.0) || isinf(nn)) {
                        for (int i2 = 0; i2 < m; ++i2) sm.wsml[i2] = (i2 == 0) ? 1.0f : 0.0f;
                    } else {
                        double inv = 1.0 / sqrt(nn);
                        for (int i2 = 0; i2 < m; ++i2) sm.wsml[i2] = (float)(sm.dp[i2] * inv);
                    }
                }
            }
        }
        __syncthreads();

        if (tid < N) {   // Ritz u = V^T wsml
            float acc = 0.f;
            for (int j = 0; j < m; ++j) acc += sm.wsml[j] * sm.V[j][tid];
            sm.v0[tid] = acc;
        }
        __syncthreads();
        if (wv == 0) {   // norm + sign-dot with uold
            float x0 = sm.v0[lane], x1 = (lane < 32) ? sm.v0[lane + 64] : 0.f;
            float u0 = sm.v4[lane], u1 = (lane < 32) ? sm.v4[lane + 64] : 0.f;
            float a = x0 * x0 + x1 * x1;
            float d = x0 * u0 + x1 * u1;
            #pragma unroll
            for (int o = 32; o; o >>= 1) { a += __shfl_xor(a, o); d += __shfl_xor(d, o); }
            if (lane == 0) { sm.scal[2] = sqrtf(a); sm.scal[3] = d; }
        }
        __syncthreads();
        {
            const float sgn = (!cold && sm.scal[3] < 0.f) ? -1.f : 1.f;
            if (tid < N) {
                float un = sgn * sm.v0[tid] / sm.scal[2];
                sm.v0[tid] = un;
                sm.u_keep[tid] = un;           // block-local warm start
                sm.v5[tid] = fabsf(un - sm.v4[tid]);
            }
        }
        __syncthreads();
        if (tid < N) {   // v = A @ u (block-local)
            const float* row = A + tid * N;
            float acc = 0.f;
            for (int k = 0; k < N; ++k) acc += row[k] * sm.v0[k];
            sm.v3[tid] = acc;
            sm.v_keep[tid] = acc;
        } else if (wv == 3) {   // conv reduce (identical in every block)
            float d0 = sm.v5[lane];
            if (lane < 32) d0 = fmaxf(d0, sm.v5[lane + 64]);
            #pragma unroll
            for (int o = 32; o; o >>= 1) d0 = fmaxf(d0, __shfl_xor(d0, o));
            if (lane == 0 && !cold && d0 < CONV_TOL) sm.convl = 1;
        }
        __syncthreads();
        {   // energy rows: tmp[i] = sum_k (F+H)[i,k] vn[k]
            const float* frow = &sm.mat[mvi * 97 + mvc * 24];
            const float* hrow = H + mvi * N + mvc * 24;
            float pp = 0.f;
            #pragma unroll
            for (int k = 0; k < 24; ++k) pp += (frow[k] + hrow[k]) * sm.v3[mvc * 24 + k];
            pp += __shfl_xor(pp, 1); pp += __shfl_xor(pp, 2);
            if (mvc == 0) sm.v0[mvi] = pp;
        }
        __syncthreads();
        if (bid == 0 && wv == 0) {
            float e = sm.v3[lane] * sm.v0[lane];
            if (lane < 32) e += sm.v3[lane + 64] * sm.v0[lane + 64];
            #pragma unroll
            for (int o = 32; o; o >>= 1) e += __shfl_xor(e, o);
            if (lane == 0) out[0] = e + Enuc[0];
        }
        if (sm.convl) break;   // identical in every block -> uniform exit
    }
}

// ===========================================================================
// FALLBACK path (round-14 proven kernels) if cooperative launch fails.
// ===========================================================================
template <int MODE>
__global__ __launch_bounds__(256)
void k_contract_fb(const float* __restrict__ G, const unsigned short* __restrict__ Gb,
                   const float* __restrict__ v,
                   float* __restrict__ J, float* __restrict__ K,
                   const int* __restrict__ conv)
{
    if (*conv) return;
    __shared__ float Ms[N * 97];
    __shared__ float vs[N];
    __shared__ float rsh[N];
    __shared__ float csh[N];
    const int tid = threadIdx.x;
    if (tid < N) vs[tid] = v[tid];
    for (int pr = blockIdx.x; pr < NPAIR_SYM; pr += (int)gridDim.x) {
        int p, q;
        decode_pq(pr, p, q);
        __syncthreads();
        if (MODE == 2) {
            const uint4* Gb4 = (const uint4*)(Gb + (size_t)pr * N2);
            for (int i = tid; i < N2 / 8; i += 256) {
                uint4 u = Gb4[i];
                int r = i / 12, s0 = (i - r * 12) * 8;
                float* dst = &Ms[r * 97 + s0];
                dst[0] = bf2f(u.x & 0xFFFFu); dst[1] = bf2f(u.x >> 16);
                dst[2] = bf2f(u.y & 0xFFFFu); dst[3] = bf2f(u.y >> 16);
                dst[4] = bf2f(u.z & 0xFFFFu); dst[5] = bf2f(u.z >> 16);
                dst[6] = bf2f(u.w & 0xFFFFu); dst[7] = bf2f(u.w >> 16);
            }
        } else {
            const float4* G4 = (const float4*)(G + (size_t)(p * N + q) * N2);
            for (int k = tid; k < N2 / 4; k += 256) {
                float4 f = G4[k];
                int r = k / 24, s4 = (k - r * 24) * 4;
                float* dst = &Ms[r * 97 + s4];
                dst[0] = f.x; dst[1] = f.y; dst[2] = f.z; dst[3] = f.w;
            }
        }
        __syncthreads();
        if (tid < N) {
            const float* row = &Ms[tid * 97];
            float acc = 0.f;
            #pragma unroll 8
            for (int s = 0; s < N; ++s) acc += row[s] * vs[s];
            atomicAdd(&K[p * N + tid], vs[q] * acc);
            rsh[tid] = acc * vs[tid];
        } else if (tid < 2 * N && p != q) {
            const int s = tid - N;
            float acc = 0.f;
            #pragma unroll 8
            for (int r = 0; r < N; ++r) acc += Ms[r * 97 + s] * vs[r];
            atomicAdd(&K[q * N + s], vs[p] * acc);
            csh[s] = acc * vs[s];
        }
        __syncthreads();
        const int lane = tid & 63, wv = tid >> 6;
        if (wv == 0) {
            float a = rsh[lane];
            if (lane < 32) a += rsh[lane + 64];
            #pragma unroll
            for (int o = 32; o; o >>= 1) a += __shfl_xor(a, o);
            if (lane == 0) J[p * N + q] = a;
        } else if (wv == 1 && p != q) {
            float a = csh[lane];
            if (lane < 32) a += csh[lane + 64];
            #pragma unroll
            for (int o = 32; o; o >>= 1) a += __shfl_xor(a, o);
            if (lane == 0) J[q * N + p] = a;
        }
    }
}

__global__ __launch_bounds__(384)
void k_eig_fb(const float* __restrict__ J, const float* __restrict__ K,
              const float* __restrict__ A, const float* __restrict__ H,
              const float* __restrict__ Enuc,
              float* __restrict__ v_ws, float* __restrict__ u_ws,
              float* __restrict__ jk, float* __restrict__ out,
              int cold, int m_max, int* __restrict__ conv)
{
    if (!cold && *conv) return;
    __shared__ SMem sm;
    const int tid  = threadIdx.x;
    const int lane = tid & 63;
    const int wv   = tid >> 6;
    if (cold && tid == 0) atomicExch(conv, 0);
    {
        const float4* H4 = (const float4*)H;
        const float4* J4 = (const float4*)J;
        const float4* K4 = (const float4*)K;
        for (int k = tid; k < N2 / 4; k += 384) {
            int r = k / 24, c4 = (k - r * 24) * 4;
            float4 h = H4[k];
            float* f = &sm.mat[r * 97 + c4];
            if (cold) { f[0] = h.x; f[1] = h.y; f[2] = h.z; f[3] = h.w; }
            else {
                float4 jj = J4[k], kk = K4[k];
                f[0] = h.x + 2.f * jj.x - kk.x;
                f[1] = h.y + 2.f * jj.y - kk.y;
                f[2] = h.z + 2.f * jj.z - kk.z;
                f[3] = h.w + 2.f * jj.w - kk.w;
            }
        }
    }
    if (tid < N) {
        float x;
        if (cold) {
            unsigned r = (unsigned)tid * 1103515245u + 12345u;
            r ^= r >> 13; r *= 2654435761u; r ^= r >> 16;
            x = (float)(r & 0xFFFFu) * (1.0f / 65536.0f) - 0.45f;
            sm.v4[tid] = 0.f;
        } else { x = u_ws[tid]; sm.v4[tid] = x; }
        sm.v0[tid] = x;
    }
    if (tid == 0) { sm.meff = m_max; sm.done = 0; sm.beta[0] = 0.f; }
    __syncthreads();
    for (int i = tid; i < 2 * N2; i += 384) jk[i] = 0.f;
    if (wv == 0) {
        float x0 = sm.v0[lane];
        float x1 = (lane < 32) ? sm.v0[lane + 64] : 0.f;
        float a = x0 * x0 + x1 * x1;
        #pragma unroll
        for (int o = 32; o; o >>= 1) a += __shfl_xor(a, o);
        float ib = 1.0f / sqrtf(a);
        sm.V[0][lane] = x0 * ib;
        if (lane < 32) sm.V[0][lane + 64] = x1 * ib;
    }
    __syncthreads();
    const int mvi = tid >> 2, mvc = tid & 3;
    for (int j = 0; j < m_max; ++j) {
        if (sm.done) break;
        {
            const float* row = A + mvi * N + mvc * 24;
            const float* src = &sm.V[j][mvc * 24];
            float pp = 0.f;
            #pragma unroll
            for (int k = 0; k < 24; ++k) pp += row[k] * src[k];
            pp += __shfl_xor(pp, 1); pp += __shfl_xor(pp, 2);
            if (mvc == 0) sm.v1[mvi] = pp;
        }
        __syncthreads();
        {
            const float* row = &sm.mat[mvi * 97 + mvc * 24];
            float pp = 0.f;
            #pragma unroll
            for (int k = 0; k < 24; ++k) pp += row[k] * sm.v1[mvc * 24 + k];
            pp += __shfl_xor(pp, 1); pp += __shfl_xor(pp, 2);
            if (mvc == 0) sm.v2[mvi] = pp;
        }
        __syncthreads();
        {
            const float* row = A + mvi * N + mvc * 24;
            float pp = 0.f;
            #pragma unroll
            for (int k = 0; k < 24; ++k) pp += row[k] * sm.v2[mvc * 24 + k];
            pp += __shfl_xor(pp, 1); pp += __shfl_xor(pp, 2);
            if (mvc == 0) sm.v0[mvi] = pp;
        }
        __syncthreads();
        for (int k = wv; k <= j; k += 6) {
            float a = sm.V[k][lane] * sm.v0[lane];
            if (lane < 32) a += sm.V[k][lane + 64] * sm.v0[lane + 64];
            #pragma unroll
            for (int o = 32; o; o >>= 1) a += __shfl_xor(a, o);
            if (lane == 0) { sm.dred[k] = a; if (k == j) sm.alpha[j] = a; }
        }
        __syncthreads();
        if (j + 1 == m_max) break;
        if (wv == 0) {
            float x0 = sm.v0[lane];
            float x1 = (lane < 32) ? sm.v0[lane + 64] : 0.f;
            for (int k = 0; k <= j; ++k) {
                float d = sm.dred[k];
                x0 -= d * sm.V[k][lane];
                if (lane < 32) x1 -= d * sm.V[k][lane + 64];
            }
            float a = x0 * x0 + x1 * x1;
            #pragma unroll
            for (int o = 32; o; o >>= 1) a += __shfl_xor(a, o);
            float b = sqrtf(a);
            if (lane == 0) sm.beta[j + 1] = b;
            if (b < 1e-5f) { if (lane == 0) { sm.meff = j + 1; sm.done = 1; } }
            else {
                float ib = 1.0f / b;
                sm.V[j + 1][lane] = x0 * ib;
                if (lane < 32) sm.V[j + 1][lane + 64] = x1 * ib;
            }
        }
        __syncthreads();
    }
    __syncthreads();
    const int m = sm.meff;
    if (wv == 0) {
        float lo_l = 3e38f, hid = 3e38f;
        if (lane < m) {
            float bl = (lane > 0) ? fabsf(sm.beta[lane]) : 0.f;
            float br = (lane + 1 < m) ? fabsf(sm.beta[lane + 1]) : 0.f;
            lo_l = sm.alpha[lane] - bl - br;
            hid  = sm.alpha[lane];
        }
        #pragma unroll
        for (int o = 32; o; o >>= 1) {
            lo_l = fminf(lo_l, __shfl_xor(lo_l, o));
            hid  = fminf(hid,  __shfl_xor(hid,  o));
        }
        float lo = lo_l - 1e-5f, hi = hid + 1e-5f;
        for (int round = 0; round < 4; ++round) {
            float x = lo + (hi - lo) * (float)(lane + 1) * (1.0f / 65.0f);
            int cnt = 0;
            float qq = sm.alpha[0] - x;
            if (qq < 0.f) cnt++;
            for (int i2 = 1; i2 < m; ++i2) {
                if (fabsf(qq) < 1e-25f) qq = (qq < 0.f) ? -1e-25f : 1e-25f;
                float bi = sm.beta[i2];
                qq = (sm.alpha[i2] - x) - bi * bi / qq;
                if (qq < 0.f) cnt++;
            }
            unsigned long long mask = __ballot(cnt >= 1);
            if (mask == 0ull) lo = lo + (hi - lo) * (64.0f / 65.0f);
            else {
                int f = __builtin_ctzll(mask);
                float xf  = lo + (hi - lo) * (float)(f + 1) * (1.0f / 65.0f);
                float xfm = lo + (hi - lo) * (float)(f)     * (1.0f / 65.0f);
                hi = xf; lo = xfm;
            }
        }
        if (lane == 0) sm.scal[1] = 0.5f * (lo + hi);
    }
    __syncthreads();
    if (tid == 0) {
        if (m == 1) sm.wsml[0] = 1.0f;
        else {
            double lam = (double)sm.scal[1] - 1e-6;
            for (int pass = 0; pass < 2; ++pass) {
                double b0 = (double)sm.alpha[0] - lam;
                if (fabs(b0) < 1e-18) b0 = (b0 < 0.0) ? -1e-18 : 1e-18;
                sm.cp[0] = (double)sm.beta[1] / b0;
                sm.dp[0] = (pass ? (double)sm.wsml[0] : 1.0) / b0;
                for (int i2 = 1; i2 < m; ++i2) {
                    double ai = (double)sm.beta[i2];
                    double md = ((double)sm.alpha[i2] - lam) - ai * sm.cp[i2 - 1];
                    if (fabs(md) < 1e-18) md = (md < 0.0) ? -1e-18 : 1e-18;
                    sm.cp[i2] = ((i2 + 1 < m) ? (double)sm.beta[i2 + 1] : 0.0) / md;
                    double rhs = pass ? (double)sm.wsml[i2] : 1.0;
                    sm.dp[i2] = (rhs - ai * sm.dp[i2 - 1]) / md;
                }
                for (int i2 = m - 2; i2 >= 0; --i2) sm.dp[i2] -= sm.cp[i2] * sm.dp[i2 + 1];
                double nn = 0.0;
                for (int i2 = 0; i2 < m; ++i2) nn += sm.dp[i2] * sm.dp[i2];
                if (!(nn > 0.0) || isinf(nn)) {
                    for (int i2 = 0; i2 < m; ++i2) sm.wsml[i2] = (i2 == 0) ? 1.0f : 0.0f;
                } else {
                    double inv = 1.0 / sqrt(nn);
                    for (int i2 = 0; i2 < m; ++i2) sm.wsml[i2] = (float)(sm.dp[i2] * inv);
                }
            }
        }
    }
    __syncthreads();
    if (tid < N) {
        float acc = 0.f;
        for (int j = 0; j < m; ++j) acc += sm.wsml[j] * sm.V[j][tid];
        sm.v0[tid] = acc;
    }
    __syncthreads();
    if (wv == 0) {
        float x0 = sm.v0[lane], x1 = (lane < 32) ? sm.v0[lane + 64] : 0.f;
        float u0 = sm.v4[lane], u1 = (lane < 32) ? sm.v4[lane + 64] : 0.f;
        float a = x0 * x0 + x1 * x1;
        float d = x0 * u0 + x1 * u1;
        #pragma unroll
        for (int o = 32; o; o >>= 1) { a += __shfl_xor(a, o); d += __shfl_xor(d, o); }
        if (lane == 0) { sm.scal[2] = sqrtf(a); sm.scal[3] = d; }
    }
    __syncthreads();
    {
        const float sgn = (!cold && sm.scal[3] < 0.f) ? -1.f : 1.f;
        if (tid < N) {
            float un = sgn * sm.v0[tid] / sm.scal[2];
            sm.v0[tid] = un;
            u_ws[tid] = un;
            sm.v5[tid] = fabsf(un - sm.v4[tid]);
        }
    }
    __syncthreads();
    if (tid < N) {
        const float* row = A + tid * N;
        float acc = 0.f;
        for (int k = 0; k < N; ++k) acc += row[k] * sm.v0[k];
        sm.v3[tid] = acc;
        v_ws[tid] = acc;
    } else if (wv == 3) {
        float d0 = sm.v5[lane];
        if (lane < 32) d0 = fmaxf(d0, sm.v5[lane + 64]);
        #pragma unroll
        for (int o = 32; o; o >>= 1) d0 = fmaxf(d0, __shfl_xor(d0, o));
        if (lane == 0 && !cold && d0 < CONV_TOL) atomicExch(conv, 1);
    }
    __syncthreads();
    {
        const float* frow = &sm.mat[mvi * 97 + mvc * 24];
        const float* hrow = H + mvi * N + mvc * 24;
        float pp = 0.f;
        #pragma unroll
        for (int k = 0; k < 24; ++k) pp += (frow[k] + hrow[k]) * sm.v3[mvc * 24 + k];
        pp += __shfl_xor(pp, 1); pp += __shfl_xor(pp, 2);
        if (mvc == 0) sm.v0[mvi] = pp;
    }
    __syncthreads();
    if (wv == 0) {
        float e = sm.v3[lane] * sm.v0[lane];
        if (lane < 32) e += sm.v3[lane + 64] * sm.v0[lane + 64];
        #pragma unroll
        for (int o = 32; o; o >>= 1) e += __shfl_xor(e, o);
        if (lane == 0) out[0] = e + Enuc[0];
    }
}

// ---------------------------------------------------------------------------
extern "C" void kernel_launch(void* const* d_in, const int* in_sizes, int n_in,
                              void* d_out, int out_size, void* d_ws, size_t ws_size,
                              hipStream_t stream)
{
    (void)in_sizes; (void)n_in; (void)out_size;
    const float* H    = (const float*)d_in[1];
    const float* A    = (const float*)d_in[2];
    const float* G    = (const float*)d_in[3];
    const float* Enuc = (const float*)d_in[4];
    float* out = (float*)d_out;
    float* ws  = (float*)d_ws;
    int*   ctr = (int*)d_ws;
    int*  conv = ctr + OFFI_CONV;
    float* jk  = ws + OFF_JK;
    float* v   = ws + OFF_V;
    float* u   = ws + OFF_U;
    unsigned short* Gb = (unsigned short*)(ws + OFF_GB);
    int bf16i = (ws_size >= NEED_BF16_BYTES) ? 1 : 0;

    k_prep<<<2048, 256, 0, stream>>>(ctr, jk, G, Gb, bf16i);

    const unsigned short* Gbc = Gb;
    void* kargs[] = { (void*)&G, (void*)&Gbc, (void*)&A, (void*)&H, (void*)&Enuc,
                      (void*)&jk, (void*)&ctr, (void*)&out, (void*)&bf16i };
    hipError_t err = hipLaunchCooperativeKernel((const void*)k_scf,
                                                dim3(FUSED_GRID), dim3(384),
                                                kargs, 0, stream);
    if (err == hipSuccess) return;
    (void)hipGetLastError();   // clear error state, take proven fallback path

    float* Jb = jk;            // buffer 0 (zeroed by k_prep; re-zeroed by eig_fb)
    float* Kb = jk + N2;
    for (int it = 0; it < MAXIT; ++it) {
        if (it > 0) {
            if (bf16i)
                k_contract_fb<2><<<FB_GRID, 256, 0, stream>>>(G, Gb, v, Jb, Kb, conv);
            else
                k_contract_fb<0><<<FB_GRID, 256, 0, stream>>>(G, Gb, v, Jb, Kb, conv);
        }
        k_eig_fb<<<1, 384, 0, stream>>>(Jb, Kb, A, H, Enuc, v, u, Jb, out,
                                        it == 0 ? 1 : 0,
                                        it == 0 ? M_COLD : M_WARM,
                                        conv);
    }
}